// Round 11
// baseline (122.820 us; speedup 1.0000x reference)
//
#include <hip/hip_runtime.h>
#include <math.h>

#define N_NODES 10000
#define N_EDGES 320000
#define DIM 256
#define BCAP 128   // edge bucket capacity per node (Poisson(32): P(>128) ~ 1e-40)

// edge partition sort parameters
#define P_PARTS 250   // dst-range partitions
#define NPP 40        // nodes per partition (250*40 = 10000)
#define PCAP 2048     // records per partition (mean 1280, >14 sigma headroom)
#define EPT 8         // edges per thread in fused pass 1 (256 thr -> 157 blocks)
#define P1_BLOCKS ((N_EDGES + 256 * EPT - 1) / (256 * EPT))  // 157

typedef __attribute__((ext_vector_type(8))) short bf16x8;
typedef __attribute__((ext_vector_type(4))) float fx4;

typedef __attribute__((address_space(3))) unsigned lds_u32;
typedef __attribute__((address_space(1))) const unsigned gbl_u32;

// ---------- helpers ----------

__device__ __forceinline__ float gelu_tanh(float x) {
  const float k0 = 0.7978845608028654f;  // sqrt(2/pi)
  float x3 = x * x * x;
  return 0.5f * x * (1.0f + tanhf(k0 * (x + 0.044715f * x3)));
}

__device__ __forceinline__ unsigned short f2bf(float f) {
  unsigned u = __float_as_uint(f);
  unsigned r = 0x7FFFu + ((u >> 16) & 1u);
  return (unsigned short)((u + r) >> 16);
}

__device__ __forceinline__ float bf_lo(unsigned u) { return __uint_as_float(u << 16); }
__device__ __forceinline__ float bf_hi(unsigned u) { return __uint_as_float(u & 0xFFFF0000u); }

// ---------- merged prep + scatter-p1 ----------
// Blocks [0, P1_BLOCKS) run edge-partition pass 1 (reads only kernel inputs,
// writes pcnt/pbuf — disjoint from prep's weight/x conversion, so the two
// overlap inside one launch). pcnt is zeroed by hipMemsetAsync beforehand.
// Remaining blocks run the weight->bf16^T / bias / x->bf16 conversions.

#define SEG_QKVS 262144
#define SEG_FF1 131072
#define SEG_FF2 131072
#define SEG_BIAS 1024
#define SEG_CONV 320000   // N*D/8
#define PREP_TOTAL (SEG_QKVS + SEG_FF1 + SEG_FF2 + SEG_BIAS + SEG_CONV)  // 845312 = 3302*256

__global__ __launch_bounds__(256) void prep_p1_kernel(
    const float* __restrict__ wq, const float* __restrict__ wk,
    const float* __restrict__ wv, const float* __restrict__ ws,
    const float* __restrict__ bq, const float* __restrict__ bk,
    const float* __restrict__ bv, const float* __restrict__ bs,
    const float* __restrict__ wff1, const float* __restrict__ wff2,
    const float* __restrict__ x,
    unsigned short* __restrict__ wt_qkvs, float* __restrict__ bias_qkvs,
    unsigned short* __restrict__ wt_ff1, unsigned short* __restrict__ wt_ff2,
    unsigned short* __restrict__ xb,
    const int* __restrict__ ei, const float* __restrict__ ew,
    const float* __restrict__ we, const float* __restrict__ be,
    unsigned* __restrict__ pcnt, uint2* __restrict__ pbuf) {
  const int tid = threadIdx.x;

  if (blockIdx.x < P1_BLOCKS) {
    // ---- edge scatter pass 1 (256-thread variant, EPT=8) ----
    __shared__ unsigned lcnt[P_PARTS];
    __shared__ unsigned lbase[P_PARTS];
    for (int i = tid; i < P_PARTS; i += 256) lcnt[i] = 0;
    __syncthreads();
    const float wes = we[0], bes = be[0];
    const int e0 = blockIdx.x * (256 * EPT);

    unsigned pp[EPT];
    unsigned rr[EPT];
    unsigned sv[EPT];
    float ebv[EPT];
#pragma unroll
    for (int j = 0; j < EPT; j++) {
      const int e = e0 + j * 256 + tid;
      pp[j] = 0;
      rr[j] = 0xFFFFFFFFu;
      if (e < N_EDGES) {
        const int dst = ei[N_EDGES + e];
        const int src = ei[e];
        const int p = dst / NPP;
        sv[j] = (unsigned)dst | ((unsigned)src << 16);
        ebv[j] = fmaf(ew[e], wes, bes);
        pp[j] = (unsigned)p;
        rr[j] = atomicAdd(&lcnt[p], 1u);
      }
    }
    __syncthreads();
    for (int i = tid; i < P_PARTS; i += 256) {
      const unsigned c = lcnt[i];
      lbase[i] = c ? atomicAdd(&pcnt[i], c) : 0u;
    }
    __syncthreads();
#pragma unroll
    for (int j = 0; j < EPT; j++) {
      if (rr[j] != 0xFFFFFFFFu) {
        const unsigned pos = lbase[pp[j]] + rr[j];
        if (pos < PCAP) {
          uint2 rec;
          rec.x = sv[j];
          rec.y = __float_as_uint(ebv[j]);
          pbuf[(size_t)pp[j] * PCAP + pos] = rec;
        }
      }
    }
    return;
  }

  // ---- conversions ----
  int id = (blockIdx.x - P1_BLOCKS) * 256 + tid;
  if (id < SEG_QKVS) {  // qkvs: [1024][256]
    const int n = id >> 8, k = id & 255;
    const float* w = (n < 256) ? wq : (n < 512) ? wk : (n < 768) ? wv : ws;
    wt_qkvs[id] = f2bf(w[k * 256 + (n & 255)]);
    return;
  }
  id -= SEG_QKVS;
  if (id < SEG_FF1) {  // ff1: [512][256]
    const int n = id >> 8, k = id & 255;
    wt_ff1[id] = f2bf(wff1[k * 512 + n]);
    return;
  }
  id -= SEG_FF1;
  if (id < SEG_FF2) {  // ff2: [256][512]
    const int n = id >> 9, k = id & 511;
    wt_ff2[id] = f2bf(wff2[k * 256 + n]);
    return;
  }
  id -= SEG_FF2;
  if (id < SEG_BIAS) {
    bias_qkvs[id] = (id < 256) ? bq[id] : (id < 512) ? bk[id & 255]
                    : (id < 768) ? bv[id & 255] : bs[id & 255];
    return;
  }
  id -= SEG_BIAS;
  if (id < SEG_CONV) {
    const int base = id * 8;
    float4 a = *(const float4*)(x + base);
    float4 b = *(const float4*)(x + base + 4);
    unsigned short h[8] = {f2bf(a.x), f2bf(a.y), f2bf(a.z), f2bf(a.w),
                           f2bf(b.x), f2bf(b.y), f2bf(b.z), f2bf(b.w)};
    *(uint4*)(xb + base) = *(const uint4*)h;
  }
}

// ---------- bf16 MFMA GEMM, 64x64 tile (r3-verified; r10 +p2-fusion) ----------
// Async global_load_lds staging, dbuf, counted vmcnt(4), swapped-operand C^T
// epilogue. SPLIT launches a flattened grid of P_PARTS + 2512 blocks: the
// first 250 run scatter pass-2 (pbuf->es_csr/cnt, disjoint from GEMM work)
// so it overlaps instead of serializing (measured r10: −7.6us total).
template <int GELU, int WF32, int WB16, int SPLIT>
__global__ __launch_bounds__(256) void mfma_gemm(
    const unsigned short* __restrict__ A, int lda,
    const unsigned short* __restrict__ Bt,
    const float* __restrict__ bias,
    const float* __restrict__ xres,
    float* __restrict__ C, int ldc,
    unsigned short* __restrict__ Cb, int ldcb,
    int M, int K,
    const unsigned* __restrict__ pcnt, const uint2* __restrict__ pbuf,
    unsigned* __restrict__ cnt, uint2* __restrict__ es_csr) {
  __shared__ char lds[32768];  // 2 buffers x (A 8KB + B 8KB); p2 aliases 160B
  const int tid = threadIdx.x;

  if (SPLIT) {
    const int bid = blockIdx.x;
    if (bid < P_PARTS) {
      // fused scatter pass 2
      unsigned* lcnt = (unsigned*)lds;
      if (tid < NPP) lcnt[tid] = 0;
      __syncthreads();
      const int n0 = bid * NPP;
      const int tot = min((int)pcnt[bid], PCAP);
      for (int i = tid; i < tot; i += 256) {
        const uint2 rec = pbuf[(size_t)bid * PCAP + i];
        const int dst = (int)(rec.x & 0xFFFFu);
        const int src = (int)(rec.x >> 16);
        const unsigned r = atomicAdd(&lcnt[dst - n0], 1u);
        if (r < BCAP) {
          uint2 o;
          o.x = (unsigned)src;
          o.y = rec.y;
          es_csr[(size_t)dst * BCAP + r] = o;
        }
      }
      __syncthreads();
      if (tid < NPP) cnt[n0 + tid] = lcnt[tid];
      return;
    }
  }

  const int l = tid & 63;
  const int wid = tid >> 6;
  const int wrow = (wid & 1) * 32;
  const int wcol = (wid >> 1) * 32;
  int bm, bn;
  if (SPLIT) {
    const int bid2 = blockIdx.x - P_PARTS;   // 0..2511
    bm = (bid2 >> 4) * 64;                   // 157 row strips
    bn = (bid2 & 15) * 64;                   // 16 col strips (N=1024)
  } else {
    bm = blockIdx.y * 64;
    bn = blockIdx.x * 64;
  }

  fx4 acc[2][2];
#pragma unroll
  for (int i = 0; i < 2; i++)
#pragma unroll
    for (int j = 0; j < 2; j++) acc[i][j] = (fx4)(0.0f);

#define STAGE(BUFOFF, KB)                                                      \
  {                                                                            \
    _Pragma("unroll") for (int i = 0; i < 2; i++) {                            \
      const int id = i * 256 + tid;                                            \
      const int row = id >> 3;                                                 \
      const int ccs = (id & 7) ^ (row & 7);                                    \
      __builtin_amdgcn_global_load_lds(                                        \
          (gbl_u32*)(A + (size_t)(bm + row) * lda + (KB) + ccs * 8),           \
          (lds_u32*)(lds + (BUFOFF) + id * 16), 16, 0, 0);                     \
    }                                                                          \
    _Pragma("unroll") for (int i = 0; i < 2; i++) {                            \
      const int id = i * 256 + tid;                                            \
      const int row = id >> 3;                                                 \
      const int ccs = (id & 7) ^ (row & 7);                                    \
      __builtin_amdgcn_global_load_lds(                                        \
          (gbl_u32*)(Bt + (size_t)(bn + row) * K + (KB) + ccs * 8),            \
          (lds_u32*)(lds + (BUFOFF) + 8192 + id * 16), 16, 0, 0);              \
    }                                                                          \
  }

  STAGE(0, 0);

  unsigned cur = 0;
  for (int kb = 0; kb < K; kb += 64) {
    if (kb + 64 < K) {
      STAGE((cur ^ 1) * 16384, kb + 64);
      asm volatile("s_waitcnt vmcnt(4)" ::: "memory");
    } else {
      asm volatile("s_waitcnt vmcnt(0)" ::: "memory");
    }
    __builtin_amdgcn_s_barrier();
    __builtin_amdgcn_sched_barrier(0);

    const char* As = lds + cur * 16384;
    const char* Bs = As + 8192;
#pragma unroll
    for (int kk = 0; kk < 2; kk++) {
      const int kbyte = (kk * 64 + ((l >> 4) << 4)) ^ ((l & 7) << 4);
      bf16x8 af[2], bg[2];
#pragma unroll
      for (int f = 0; f < 2; f++) {
        const int ar = wrow + f * 16 + (l & 15);
        af[f] = *(const bf16x8*)(As + ar * 128 + kbyte);
        const int br = wcol + f * 16 + (l & 15);
        bg[f] = *(const bf16x8*)(Bs + br * 128 + kbyte);
      }
      // operands swapped -> C^T fragment (thread holds 4 consecutive n)
#pragma unroll
      for (int fr = 0; fr < 2; fr++)
#pragma unroll
        for (int fc = 0; fc < 2; fc++)
          acc[fr][fc] = __builtin_amdgcn_mfma_f32_16x16x32_bf16(
              bg[fc], af[fr], acc[fr][fc], 0, 0, 0);
    }
    __builtin_amdgcn_s_barrier();
    cur ^= 1;
  }
#undef STAGE

  // epilogue (transposed fragments): m fixed per thread, n0..n0+3 in regs
#pragma unroll
  for (int fr = 0; fr < 2; fr++) {
    const int m = bm + wrow + fr * 16 + (l & 15);
    if (m < M) {
#pragma unroll
      for (int fc = 0; fc < 2; fc++) {
        const int n0 = bn + wcol + fc * 16 + ((l >> 4) << 2);
        const float4 b4 = *(const float4*)(bias + n0);
        fx4 v = acc[fr][fc];
        float o0 = v[0] + b4.x;
        float o1 = v[1] + b4.y;
        float o2 = v[2] + b4.z;
        float o3 = v[3] + b4.w;
        if (GELU) {
          o0 = gelu_tanh(o0); o1 = gelu_tanh(o1);
          o2 = gelu_tanh(o2); o3 = gelu_tanh(o3);
        }
        if (SPLIT) {
          const int seg = n0 >> 8, nn = n0 & 255;
          if (seg == 3) {
            const float4 xr = *(const float4*)(xres + (size_t)m * 256 + nn);
            float4 w;
            w.x = o0 + xr.x; w.y = o1 + xr.y; w.z = o2 + xr.z; w.w = o3 + xr.w;
            *(float4*)(C + (size_t)m * 256 + nn) = w;
          } else {
            uint2 pk;
            pk.x = (unsigned)f2bf(o0) | ((unsigned)f2bf(o1) << 16);
            pk.y = (unsigned)f2bf(o2) | ((unsigned)f2bf(o3) << 16);
            *(uint2*)(Cb + (size_t)seg * (N_NODES * DIM) + (size_t)m * 256 + nn) = pk;
          }
        } else {
          if (WF32) {
            float4 w; w.x = o0; w.y = o1; w.z = o2; w.w = o3;
            *(float4*)(C + (size_t)m * ldc + n0) = w;
          }
          if (WB16) {
            uint2 pk;
            pk.x = (unsigned)f2bf(o0) | ((unsigned)f2bf(o1) << 16);
            pk.y = (unsigned)f2bf(o2) | ((unsigned)f2bf(o3) << 16);
            *(uint2*)(Cb + (size_t)m * ldcb + n0) = pk;
          }
        }
      }
    }
  }
}

// ---------- agg: 4 independent waves (nodes) per 256-thread block ----------
// Was 10000 x 64-thread blocks = 1 wave/block; workgroup-slot limits cap
// ~16 blocks/CU -> only ~16 waves/CU for a latency-bound random-gather
// kernel. Packing 4 waves/block doubles achievable TLP; waves never
// interact (no barriers), per-wave code unchanged.
__global__ __launch_bounds__(256) void agg_fused_kernel(
    const unsigned* __restrict__ cnt, const uint2* __restrict__ es_csr,
    const unsigned short* __restrict__ qb,
    const unsigned short* __restrict__ kb, const unsigned short* __restrict__ vb,
    const float* __restrict__ sbuf,
    const float* __restrict__ g, const float* __restrict__ b,
    float* __restrict__ out, unsigned short* __restrict__ outb) {
  const int node = blockIdx.x * 4 + (threadIdx.x >> 6);
  const int lane = threadIdx.x & 63;
  const int grp = lane >> 4;   // 0..3
  const int t = lane & 15;     // 16-elem chunk index
  const int start = node * BCAP;
  const int deg = min((int)cnt[node], BCAP);
  const int end = start + deg;

  const uint4 qA = *(const uint4*)(qb + (size_t)node * 256 + t * 16);
  const uint4 qB = *(const uint4*)(qb + (size_t)node * 256 + t * 16 + 8);
  float qf[16];
  qf[0] = bf_lo(qA.x);  qf[1] = bf_hi(qA.x);
  qf[2] = bf_lo(qA.y);  qf[3] = bf_hi(qA.y);
  qf[4] = bf_lo(qA.z);  qf[5] = bf_hi(qA.z);
  qf[6] = bf_lo(qA.w);  qf[7] = bf_hi(qA.w);
  qf[8] = bf_lo(qB.x);  qf[9] = bf_hi(qB.x);
  qf[10] = bf_lo(qB.y); qf[11] = bf_hi(qB.y);
  qf[12] = bf_lo(qB.z); qf[13] = bf_hi(qB.z);
  qf[14] = bf_lo(qB.w); qf[15] = bf_hi(qB.w);

  float m = -3.4e38f, dsum = 0.f;
  float a0 = 0.f, a1 = 0.f, a2 = 0.f, a3 = 0.f;

  int ea = start + grp * 2;
  int eb_ = ea + 1;
  bool va = ea < end, vbd = eb_ < end;
  int sa = 0, sb = 0;
  float ba = 0.f, bb = 0.f;
  if (va) { const uint2 es = es_csr[ea]; sa = (int)es.x; ba = __uint_as_float(es.y); }
  if (vbd) { const uint2 es = es_csr[eb_]; sb = (int)es.x; bb = __uint_as_float(es.y); }
  uint4 kAa = *(const uint4*)(kb + (size_t)sa * 256 + t * 16);
  uint4 kBa = *(const uint4*)(kb + (size_t)sa * 256 + t * 16 + 8);
  uint4 kAb = *(const uint4*)(kb + (size_t)sb * 256 + t * 16);
  uint4 kBb = *(const uint4*)(kb + (size_t)sb * 256 + t * 16 + 8);

  for (int base = start; base < end; base += 8) {
    const int s0 = __shfl(sa, 0), s1 = __shfl(sa, 16);
    const int s2 = __shfl(sa, 32), s3 = __shfl(sa, 48);
    const int s4 = __shfl(sb, 0), s5 = __shfl(sb, 16);
    const int s6 = __shfl(sb, 32), s7 = __shfl(sb, 48);
    const uint2 v0 = *(const uint2*)(vb + (size_t)s0 * 256 + lane * 4);
    const uint2 v1 = *(const uint2*)(vb + (size_t)s1 * 256 + lane * 4);
    const uint2 v2 = *(const uint2*)(vb + (size_t)s2 * 256 + lane * 4);
    const uint2 v3 = *(const uint2*)(vb + (size_t)s3 * 256 + lane * 4);
    const uint2 v4 = *(const uint2*)(vb + (size_t)s4 * 256 + lane * 4);
    const uint2 v5 = *(const uint2*)(vb + (size_t)s5 * 256 + lane * 4);
    const uint2 v6 = *(const uint2*)(vb + (size_t)s6 * 256 + lane * 4);
    const uint2 v7 = *(const uint2*)(vb + (size_t)s7 * 256 + lane * 4);

    const int na = base + 8 + grp * 2;
    const int nb = na + 1;
    const bool va_n = na < end, vb_n = nb < end;
    int sa_n = 0, sb_n = 0;
    float ba_n = 0.f, bb_n = 0.f;
    if (va_n) { const uint2 es = es_csr[na]; sa_n = (int)es.x; ba_n = __uint_as_float(es.y); }
    if (vb_n) { const uint2 es = es_csr[nb]; sb_n = (int)es.x; bb_n = __uint_as_float(es.y); }

    float da = qf[0] * bf_lo(kAa.x);
    float db = qf[0] * bf_lo(kAb.x);
    da = fmaf(qf[1], bf_hi(kAa.x), da);  db = fmaf(qf[1], bf_hi(kAb.x), db);
    da = fmaf(qf[2], bf_lo(kAa.y), da);  db = fmaf(qf[2], bf_lo(kAb.y), db);
    da = fmaf(qf[3], bf_hi(kAa.y), da);  db = fmaf(qf[3], bf_hi(kAb.y), db);
    da = fmaf(qf[4], bf_lo(kAa.z), da);  db = fmaf(qf[4], bf_lo(kAb.z), db);
    da = fmaf(qf[5], bf_hi(kAa.z), da);  db = fmaf(qf[5], bf_hi(kAb.z), db);
    da = fmaf(qf[6], bf_lo(kAa.w), da);  db = fmaf(qf[6], bf_lo(kAb.w), db);
    da = fmaf(qf[7], bf_hi(kAa.w), da);  db = fmaf(qf[7], bf_hi(kAb.w), db);
    da = fmaf(qf[8], bf_lo(kBa.x), da);  db = fmaf(qf[8], bf_lo(kBb.x), db);
    da = fmaf(qf[9], bf_hi(kBa.x), da);  db = fmaf(qf[9], bf_hi(kBb.x), db);
    da = fmaf(qf[10], bf_lo(kBa.y), da); db = fmaf(qf[10], bf_lo(kBb.y), db);
    da = fmaf(qf[11], bf_hi(kBa.y), da); db = fmaf(qf[11], bf_hi(kBb.y), db);
    da = fmaf(qf[12], bf_lo(kBa.z), da); db = fmaf(qf[12], bf_lo(kBb.z), db);
    da = fmaf(qf[13], bf_hi(kBa.z), da); db = fmaf(qf[13], bf_hi(kBb.z), db);
    da = fmaf(qf[14], bf_lo(kBa.w), da); db = fmaf(qf[14], bf_lo(kBb.w), db);
    da = fmaf(qf[15], bf_hi(kBa.w), da); db = fmaf(qf[15], bf_hi(kBb.w), db);
    da += __shfl_xor(da, 1);  db += __shfl_xor(db, 1);
    da += __shfl_xor(da, 2);  db += __shfl_xor(db, 2);
    da += __shfl_xor(da, 4);  db += __shfl_xor(db, 4);
    da += __shfl_xor(da, 8);  db += __shfl_xor(db, 8);
    const float sca = va ? fmaf(da, 0.0625f, ba) : -3.4e38f;
    const float scb = vbd ? fmaf(db, 0.0625f, bb) : -3.4e38f;

    const uint4 kAa_n = *(const uint4*)(kb + (size_t)sa_n * 256 + t * 16);
    const uint4 kBa_n = *(const uint4*)(kb + (size_t)sa_n * 256 + t * 16 + 8);
    const uint4 kAb_n = *(const uint4*)(kb + (size_t)sb_n * 256 + t * 16);
    const uint4 kBb_n = *(const uint4*)(kb + (size_t)sb_n * 256 + t * 16 + 8);

    const float c0 = __shfl(sca, 0), c1 = __shfl(sca, 16);
    const float c2 = __shfl(sca, 32), c3 = __shfl(sca, 48);
    const float c4 = __shfl(scb, 0), c5 = __shfl(scb, 16);
    const float c6 = __shfl(scb, 32), c7 = __shfl(scb, 48);

    const float mx = fmaxf(fmaxf(fmaxf(c0, c1), fmaxf(c2, c3)),
                           fmaxf(fmaxf(c4, c5), fmaxf(c6, c7)));
    const float mn = fmaxf(m, mx);
    const float scale = __expf(m - mn);
    const float w0 = __expf(c0 - mn), w1 = __expf(c1 - mn);
    const float w2 = __expf(c2 - mn), w3 = __expf(c3 - mn);
    const float w4 = __expf(c4 - mn), w5 = __expf(c5 - mn);
    const float w6 = __expf(c6 - mn), w7 = __expf(c7 - mn);
    dsum = fmaf(dsum, scale, ((w0 + w1) + (w2 + w3)) + ((w4 + w5) + (w6 + w7)));

    float t0 = a0 * scale;
    t0 = fmaf(w0, bf_lo(v0.x), t0); t0 = fmaf(w1, bf_lo(v1.x), t0);
    t0 = fmaf(w2, bf_lo(v2.x), t0); t0 = fmaf(w3, bf_lo(v3.x), t0);
    t0 = fmaf(w4, bf_lo(v4.x), t0); t0 = fmaf(w5, bf_lo(v5.x), t0);
    t0 = fmaf(w6, bf_lo(v6.x), t0); t0 = fmaf(w7, bf_lo(v7.x), t0);
    a0 = t0;
    float t1 = a1 * scale;
    t1 = fmaf(w0, bf_hi(v0.x), t1); t1 = fmaf(w1, bf_hi(v1.x), t1);
    t1 = fmaf(w2, bf_hi(v2.x), t1); t1 = fmaf(w3, bf_hi(v3.x), t1);
    t1 = fmaf(w4, bf_hi(v4.x), t1); t1 = fmaf(w5, bf_hi(v5.x), t1);
    t1 = fmaf(w6, bf_hi(v6.x), t1); t1 = fmaf(w7, bf_hi(v7.x), t1);
    a1 = t1;
    float t2 = a2 * scale;
    t2 = fmaf(w0, bf_lo(v0.y), t2); t2 = fmaf(w1, bf_lo(v1.y), t2);
    t2 = fmaf(w2, bf_lo(v2.y), t2); t2 = fmaf(w3, bf_lo(v3.y), t2);
    t2 = fmaf(w4, bf_lo(v4.y), t2); t2 = fmaf(w5, bf_lo(v5.y), t2);
    t2 = fmaf(w6, bf_lo(v6.y), t2); t2 = fmaf(w7, bf_lo(v7.y), t2);
    a2 = t2;
    float t3 = a3 * scale;
    t3 = fmaf(w0, bf_hi(v0.y), t3); t3 = fmaf(w1, bf_hi(v1.y), t3);
    t3 = fmaf(w2, bf_hi(v2.y), t3); t3 = fmaf(w3, bf_hi(v3.y), t3);
    t3 = fmaf(w4, bf_hi(v4.y), t3); t3 = fmaf(w5, bf_hi(v5.y), t3);
    t3 = fmaf(w6, bf_hi(v6.y), t3); t3 = fmaf(w7, bf_hi(v7.y), t3);
    a3 = t3;
    m = mn;

    sa = sa_n; sb = sb_n;
    ba = ba_n; bb = bb_n;
    va = va_n; vbd = vb_n;
    kAa = kAa_n; kBa = kBa_n;
    kAb = kAb_n; kBb = kBb_n;
  }
  const float inv = 1.0f / fmaxf(dsum, 1e-12f);

  const float4 sv = *(const float4*)(sbuf + (size_t)node * 256 + lane * 4);
  float r0 = a0 * inv + sv.x;
  float r1 = a1 * inv + sv.y;
  float r2 = a2 * inv + sv.z;
  float r3 = a3 * inv + sv.w;

  float sum = r0 + r1 + r2 + r3;
#pragma unroll
  for (int off = 32; off > 0; off >>= 1) sum += __shfl_xor(sum, off);
  const float mu = sum * (1.0f / 256.0f);
  const float d0 = r0 - mu, d1 = r1 - mu, d2 = r2 - mu, d3 = r3 - mu;
  float vs = d0 * d0 + d1 * d1 + d2 * d2 + d3 * d3;
#pragma unroll
  for (int off = 32; off > 0; off >>= 1) vs += __shfl_xor(vs, off);
  const float rs = rsqrtf(vs * (1.0f / 256.0f) + 1e-5f);

  const float4 gv = *(const float4*)(g + lane * 4);
  const float4 bv = *(const float4*)(b + lane * 4);
  float4 o;
  o.x = d0 * rs * gv.x + bv.x;
  o.y = d1 * rs * gv.y + bv.y;
  o.z = d2 * rs * gv.z + bv.z;
  o.w = d3 * rs * gv.w + bv.w;
  *(float4*)(out + (size_t)node * 256 + lane * 4) = o;
  uint2 pk;
  pk.x = (unsigned)f2bf(o.x) | ((unsigned)f2bf(o.y) << 16);
  pk.y = (unsigned)f2bf(o.z) | ((unsigned)f2bf(o.w) << 16);
  *(uint2*)(outb + (size_t)node * 256 + lane * 4) = pk;
}

// ---------- LN2 ----------

__global__ __launch_bounds__(256) void ln2_kernel(
    const float* __restrict__ x1, const float* __restrict__ y,
    const float* __restrict__ g, const float* __restrict__ b,
    float* __restrict__ out) {
  __shared__ float red[4];
  const int row = blockIdx.x;
  const int t = threadIdx.x;
  float v = x1[(size_t)row * 256 + t] + y[(size_t)row * 256 + t];
  float s = v;
#pragma unroll
  for (int off = 32; off > 0; off >>= 1) s += __shfl_xor(s, off);
  if ((t & 63) == 0) red[t >> 6] = s;
  __syncthreads();
  float tot = red[0] + red[1] + red[2] + red[3];
  __syncthreads();
  const float mu = tot * (1.0f / 256.0f);
  const float d = v - mu;
  float vs = d * d;
#pragma unroll
  for (int off = 32; off > 0; off >>= 1) vs += __shfl_xor(vs, off);
  if ((t & 63) == 0) red[t >> 6] = vs;
  __syncthreads();
  float vtot = red[0] + red[1] + red[2] + red[3];
  const float r = rsqrtf(vtot * (1.0f / 256.0f) + 1e-5f);
  out[(size_t)row * 256 + t] = d * r * g[t] + b[t];
}

// ---------- launch ----------

extern "C" void kernel_launch(void* const* d_in, const int* in_sizes, int n_in,
                              void* d_out, int out_size, void* d_ws,
                              size_t ws_size, hipStream_t stream) {
  const float* x = (const float*)d_in[0];
  const int* ei = (const int*)d_in[1];
  const float* ew = (const float*)d_in[2];
  const float* wq = (const float*)d_in[3];
  const float* bq = (const float*)d_in[4];
  const float* wk = (const float*)d_in[5];
  const float* bk = (const float*)d_in[6];
  const float* wv = (const float*)d_in[7];
  const float* bv = (const float*)d_in[8];
  const float* wsm = (const float*)d_in[9];
  const float* bs = (const float*)d_in[10];
  const float* we = (const float*)d_in[11];
  const float* be = (const float*)d_in[12];
  const float* g1 = (const float*)d_in[13];
  const float* b1 = (const float*)d_in[14];
  const float* g2 = (const float*)d_in[15];
  const float* b2 = (const float*)d_in[16];
  const float* wff1 = (const float*)d_in[17];
  const float* bff1 = (const float*)d_in[18];
  const float* wff2 = (const float*)d_in[19];
  const float* bff2 = (const float*)d_in[20];
  float* out = (float*)d_out;

  unsigned short* qb = (unsigned short*)d_ws;        // 3 * N*256 bf16 (q,k,v)
  unsigned short* kbp = qb + 2560000;
  unsigned short* vbp = qb + 5120000;
  float* sbuf = (float*)(qb + 7680000);              // N*256 f32 (x + skip)
  uint2* es_csr = (uint2*)(sbuf + 2560000);          // N*BCAP x {src, eb}
  unsigned* cnt = (unsigned*)(es_csr + (size_t)N_NODES * BCAP);  // N
  float* x1 = (float*)(cnt + N_NODES);               // N*256
  float* y = x1 + 2560000;                           // N*256
  unsigned short* x1b = (unsigned short*)(y + 2560000);  // N*256 bf16
  unsigned short* h_b = x1b + 2560000;               // N*512 bf16
  unsigned short* xb = h_b;                          // alias (xb dead before h_b written)
  unsigned short* wt_qkvs = h_b + 5120000;           // 262144
  unsigned short* wt_ff1 = wt_qkvs + 262144;         // 131072
  unsigned short* wt_ff2 = wt_ff1 + 131072;          // 131072
  float* bias_qkvs = (float*)(wt_ff2 + 131072);      // 1024
  unsigned* pcnt = (unsigned*)(bias_qkvs + 1024);    // 256 (partition counters)
  uint2* pbuf = (uint2*)(pcnt + 256);                // P_PARTS*PCAP records (4MB)

  dim3 blk(256);
  const int mb = (N_NODES + 63) / 64;  // 157

  // zero partition counters (graph-capturable async memset), then the merged
  // prep + scatter-p1 kernel (p1 overlaps with conversions in one launch)
  hipMemsetAsync(pcnt, 0, P_PARTS * sizeof(unsigned), stream);
  prep_p1_kernel<<<P1_BLOCKS + PREP_TOTAL / 256, blk, 0, stream>>>(
      wq, wk, wv, wsm, bq, bk, bv, bs, wff1, wff2, x,
      wt_qkvs, bias_qkvs, wt_ff1, wt_ff2, xb,
      ei, ew, we, be, pcnt, pbuf);

  // q,k,v (bf16) + sbuf = x + x@ws + bs (f32), scatter pass-2 fused as the
  // first 250 blocks of the flattened grid (overlaps with GEMM)
  mfma_gemm<0, 0, 0, 1><<<dim3(P_PARTS + 16 * mb), blk, 0, stream>>>(
      xb, 256, wt_qkvs, bias_qkvs, x, sbuf, 0, qb, 0, N_NODES, 256,
      pcnt, pbuf, cnt, es_csr);

  agg_fused_kernel<<<dim3(N_NODES / 4), blk, 0, stream>>>(
      cnt, es_csr, qb, kbp, vbp, sbuf, g1, b1, x1, x1b);

  // h = gelu(x1 @ wff1 + bff1) (bf16)  [64^2 tile, (8,157)]
  mfma_gemm<1, 0, 1, 0><<<dim3(8, mb), blk, 0, stream>>>(
      x1b, 256, wt_ff1, bff1, nullptr, (float*)nullptr, 0, h_b, 512, N_NODES, 256,
      nullptr, nullptr, nullptr, nullptr);

  // y = h @ wff2 + bff2 (f32)  [64^2 tile, (4,157)]
  mfma_gemm<0, 1, 0, 0><<<dim3(4, mb), blk, 0, stream>>>(
      h_b, 512, wt_ff2, bff2, nullptr, y, 256, (unsigned short*)nullptr, 0, N_NODES, 512,
      nullptr, nullptr, nullptr, nullptr);

  ln2_kernel<<<N_NODES, blk, 0, stream>>>(x1, y, g2, b2, out);
}

// Round 12
// 121.970 us; speedup vs baseline: 1.0070x; 1.0070x over previous
//
#include <hip/hip_runtime.h>
#include <math.h>

#define N_NODES 10000
#define N_EDGES 320000
#define DIM 256
#define BCAP 128   // edge bucket capacity per node (Poisson(32): P(>128) ~ 1e-40)

// edge partition sort parameters
#define P_PARTS 250   // dst-range partitions
#define NPP 40        // nodes per partition (250*40 = 10000)
#define PCAP 2048     // records per partition (mean 1280, >14 sigma headroom)
#define EPT 8         // edges per thread in fused pass 1 (256 thr -> 157 blocks)
#define P1_BLOCKS ((N_EDGES + 256 * EPT - 1) / (256 * EPT))  // 157

typedef __attribute__((ext_vector_type(8))) short bf16x8;
typedef __attribute__((ext_vector_type(4))) float fx4;

typedef __attribute__((address_space(3))) unsigned lds_u32;
typedef __attribute__((address_space(1))) const unsigned gbl_u32;

// ---------- helpers ----------

__device__ __forceinline__ float gelu_tanh(float x) {
  const float k0 = 0.7978845608028654f;  // sqrt(2/pi)
  float x3 = x * x * x;
  return 0.5f * x * (1.0f + tanhf(k0 * (x + 0.044715f * x3)));
}

__device__ __forceinline__ unsigned short f2bf(float f) {
  unsigned u = __float_as_uint(f);
  unsigned r = 0x7FFFu + ((u >> 16) & 1u);
  return (unsigned short)((u + r) >> 16);
}

__device__ __forceinline__ float bf_lo(unsigned u) { return __uint_as_float(u << 16); }
__device__ __forceinline__ float bf_hi(unsigned u) { return __uint_as_float(u & 0xFFFF0000u); }

// ---------- merged prep + scatter-p1 (kept from r11) ----------
// Blocks [0, P1_BLOCKS) run edge-partition pass 1 (reads only kernel inputs,
// writes pcnt/pbuf — disjoint from prep's weight/x conversion, so the two
// overlap inside one launch). pcnt is zeroed by hipMemsetAsync beforehand.

#define SEG_QKVS 262144
#define SEG_FF1 131072
#define SEG_FF2 131072
#define SEG_BIAS 1024
#define SEG_CONV 320000   // N*D/8
#define PREP_TOTAL (SEG_QKVS + SEG_FF1 + SEG_FF2 + SEG_BIAS + SEG_CONV)  // 845312 = 3302*256

__global__ __launch_bounds__(256) void prep_p1_kernel(
    const float* __restrict__ wq, const float* __restrict__ wk,
    const float* __restrict__ wv, const float* __restrict__ ws,
    const float* __restrict__ bq, const float* __restrict__ bk,
    const float* __restrict__ bv, const float* __restrict__ bs,
    const float* __restrict__ wff1, const float* __restrict__ wff2,
    const float* __restrict__ x,
    unsigned short* __restrict__ wt_qkvs, float* __restrict__ bias_qkvs,
    unsigned short* __restrict__ wt_ff1, unsigned short* __restrict__ wt_ff2,
    unsigned short* __restrict__ xb,
    const int* __restrict__ ei, const float* __restrict__ ew,
    const float* __restrict__ we, const float* __restrict__ be,
    unsigned* __restrict__ pcnt, uint2* __restrict__ pbuf) {
  const int tid = threadIdx.x;

  if (blockIdx.x < P1_BLOCKS) {
    // ---- edge scatter pass 1 (256-thread variant, EPT=8) ----
    __shared__ unsigned lcnt[P_PARTS];
    __shared__ unsigned lbase[P_PARTS];
    for (int i = tid; i < P_PARTS; i += 256) lcnt[i] = 0;
    __syncthreads();
    const float wes = we[0], bes = be[0];
    const int e0 = blockIdx.x * (256 * EPT);

    unsigned pp[EPT];
    unsigned rr[EPT];
    unsigned sv[EPT];
    float ebv[EPT];
#pragma unroll
    for (int j = 0; j < EPT; j++) {
      const int e = e0 + j * 256 + tid;
      pp[j] = 0;
      rr[j] = 0xFFFFFFFFu;
      if (e < N_EDGES) {
        const int dst = ei[N_EDGES + e];
        const int src = ei[e];
        const int p = dst / NPP;
        sv[j] = (unsigned)dst | ((unsigned)src << 16);
        ebv[j] = fmaf(ew[e], wes, bes);
        pp[j] = (unsigned)p;
        rr[j] = atomicAdd(&lcnt[p], 1u);
      }
    }
    __syncthreads();
    for (int i = tid; i < P_PARTS; i += 256) {
      const unsigned c = lcnt[i];
      lbase[i] = c ? atomicAdd(&pcnt[i], c) : 0u;
    }
    __syncthreads();
#pragma unroll
    for (int j = 0; j < EPT; j++) {
      if (rr[j] != 0xFFFFFFFFu) {
        const unsigned pos = lbase[pp[j]] + rr[j];
        if (pos < PCAP) {
          uint2 rec;
          rec.x = sv[j];
          rec.y = __float_as_uint(ebv[j]);
          pbuf[(size_t)pp[j] * PCAP + pos] = rec;
        }
      }
    }
    return;
  }

  // ---- conversions ----
  int id = (blockIdx.x - P1_BLOCKS) * 256 + tid;
  if (id < SEG_QKVS) {  // qkvs: [1024][256]
    const int n = id >> 8, k = id & 255;
    const float* w = (n < 256) ? wq : (n < 512) ? wk : (n < 768) ? wv : ws;
    wt_qkvs[id] = f2bf(w[k * 256 + (n & 255)]);
    return;
  }
  id -= SEG_QKVS;
  if (id < SEG_FF1) {  // ff1: [512][256]
    const int n = id >> 8, k = id & 255;
    wt_ff1[id] = f2bf(wff1[k * 512 + n]);
    return;
  }
  id -= SEG_FF1;
  if (id < SEG_FF2) {  // ff2: [256][512]
    const int n = id >> 9, k = id & 511;
    wt_ff2[id] = f2bf(wff2[k * 256 + n]);
    return;
  }
  id -= SEG_FF2;
  if (id < SEG_BIAS) {
    bias_qkvs[id] = (id < 256) ? bq[id] : (id < 512) ? bk[id & 255]
                    : (id < 768) ? bv[id & 255] : bs[id & 255];
    return;
  }
  id -= SEG_BIAS;
  if (id < SEG_CONV) {
    const int base = id * 8;
    float4 a = *(const float4*)(x + base);
    float4 b = *(const float4*)(x + base + 4);
    unsigned short h[8] = {f2bf(a.x), f2bf(a.y), f2bf(a.z), f2bf(a.w),
                           f2bf(b.x), f2bf(b.y), f2bf(b.z), f2bf(b.w)};
    *(uint4*)(xb + base) = *(const uint4*)h;
  }
}

// ---------- bf16 MFMA GEMM, 64x64 tile (r3-verified; r10 +p2-fusion) ----------
template <int GELU, int WF32, int WB16, int SPLIT>
__global__ __launch_bounds__(256) void mfma_gemm(
    const unsigned short* __restrict__ A, int lda,
    const unsigned short* __restrict__ Bt,
    const float* __restrict__ bias,
    const float* __restrict__ xres,
    float* __restrict__ C, int ldc,
    unsigned short* __restrict__ Cb, int ldcb,
    int M, int K,
    const unsigned* __restrict__ pcnt, const uint2* __restrict__ pbuf,
    unsigned* __restrict__ cnt, uint2* __restrict__ es_csr) {
  __shared__ char lds[32768];  // 2 buffers x (A 8KB + B 8KB); p2 aliases 160B
  const int tid = threadIdx.x;

  if (SPLIT) {
    const int bid = blockIdx.x;
    if (bid < P_PARTS) {
      // fused scatter pass 2
      unsigned* lcnt = (unsigned*)lds;
      if (tid < NPP) lcnt[tid] = 0;
      __syncthreads();
      const int n0 = bid * NPP;
      const int tot = min((int)pcnt[bid], PCAP);
      for (int i = tid; i < tot; i += 256) {
        const uint2 rec = pbuf[(size_t)bid * PCAP + i];
        const int dst = (int)(rec.x & 0xFFFFu);
        const int src = (int)(rec.x >> 16);
        const unsigned r = atomicAdd(&lcnt[dst - n0], 1u);
        if (r < BCAP) {
          uint2 o;
          o.x = (unsigned)src;
          o.y = rec.y;
          es_csr[(size_t)dst * BCAP + r] = o;
        }
      }
      __syncthreads();
      if (tid < NPP) cnt[n0 + tid] = lcnt[tid];
      return;
    }
  }

  const int l = tid & 63;
  const int wid = tid >> 6;
  const int wrow = (wid & 1) * 32;
  const int wcol = (wid >> 1) * 32;
  int bm, bn;
  if (SPLIT) {
    const int bid2 = blockIdx.x - P_PARTS;   // 0..2511
    bm = (bid2 >> 4) * 64;                   // 157 row strips
    bn = (bid2 & 15) * 64;                   // 16 col strips (N=1024)
  } else {
    bm = blockIdx.y * 64;
    bn = blockIdx.x * 64;
  }

  fx4 acc[2][2];
#pragma unroll
  for (int i = 0; i < 2; i++)
#pragma unroll
    for (int j = 0; j < 2; j++) acc[i][j] = (fx4)(0.0f);

#define STAGE(BUFOFF, KB)                                                      \
  {                                                                            \
    _Pragma("unroll") for (int i = 0; i < 2; i++) {                            \
      const int id = i * 256 + tid;                                            \
      const int row = id >> 3;                                                 \
      const int ccs = (id & 7) ^ (row & 7);                                    \
      __builtin_amdgcn_global_load_lds(                                        \
          (gbl_u32*)(A + (size_t)(bm + row) * lda + (KB) + ccs * 8),           \
          (lds_u32*)(lds + (BUFOFF) + id * 16), 16, 0, 0);                     \
    }                                                                          \
    _Pragma("unroll") for (int i = 0; i < 2; i++) {                            \
      const int id = i * 256 + tid;                                            \
      const int row = id >> 3;                                                 \
      const int ccs = (id & 7) ^ (row & 7);                                    \
      __builtin_amdgcn_global_load_lds(                                        \
          (gbl_u32*)(Bt + (size_t)(bn + row) * K + (KB) + ccs * 8),            \
          (lds_u32*)(lds + (BUFOFF) + 8192 + id * 16), 16, 0, 0);              \
    }                                                                          \
  }

  STAGE(0, 0);

  unsigned cur = 0;
  for (int kb = 0; kb < K; kb += 64) {
    if (kb + 64 < K) {
      STAGE((cur ^ 1) * 16384, kb + 64);
      asm volatile("s_waitcnt vmcnt(4)" ::: "memory");
    } else {
      asm volatile("s_waitcnt vmcnt(0)" ::: "memory");
    }
    __builtin_amdgcn_s_barrier();
    __builtin_amdgcn_sched_barrier(0);

    const char* As = lds + cur * 16384;
    const char* Bs = As + 8192;
#pragma unroll
    for (int kk = 0; kk < 2; kk++) {
      const int kbyte = (kk * 64 + ((l >> 4) << 4)) ^ ((l & 7) << 4);
      bf16x8 af[2], bg[2];
#pragma unroll
      for (int f = 0; f < 2; f++) {
        const int ar = wrow + f * 16 + (l & 15);
        af[f] = *(const bf16x8*)(As + ar * 128 + kbyte);
        const int br = wcol + f * 16 + (l & 15);
        bg[f] = *(const bf16x8*)(Bs + br * 128 + kbyte);
      }
      // operands swapped -> C^T fragment (thread holds 4 consecutive n)
#pragma unroll
      for (int fr = 0; fr < 2; fr++)
#pragma unroll
        for (int fc = 0; fc < 2; fc++)
          acc[fr][fc] = __builtin_amdgcn_mfma_f32_16x16x32_bf16(
              bg[fc], af[fr], acc[fr][fc], 0, 0, 0);
    }
    __builtin_amdgcn_s_barrier();
    cur ^= 1;
  }
#undef STAGE

  // epilogue (transposed fragments): m fixed per thread, n0..n0+3 in regs
#pragma unroll
  for (int fr = 0; fr < 2; fr++) {
    const int m = bm + wrow + fr * 16 + (l & 15);
    if (m < M) {
#pragma unroll
      for (int fc = 0; fc < 2; fc++) {
        const int n0 = bn + wcol + fc * 16 + ((l >> 4) << 2);
        const float4 b4 = *(const float4*)(bias + n0);
        fx4 v = acc[fr][fc];
        float o0 = v[0] + b4.x;
        float o1 = v[1] + b4.y;
        float o2 = v[2] + b4.z;
        float o3 = v[3] + b4.w;
        if (GELU) {
          o0 = gelu_tanh(o0); o1 = gelu_tanh(o1);
          o2 = gelu_tanh(o2); o3 = gelu_tanh(o3);
        }
        if (SPLIT) {
          const int seg = n0 >> 8, nn = n0 & 255;
          if (seg == 3) {
            const float4 xr = *(const float4*)(xres + (size_t)m * 256 + nn);
            float4 w;
            w.x = o0 + xr.x; w.y = o1 + xr.y; w.z = o2 + xr.z; w.w = o3 + xr.w;
            *(float4*)(C + (size_t)m * 256 + nn) = w;
          } else {
            uint2 pk;
            pk.x = (unsigned)f2bf(o0) | ((unsigned)f2bf(o1) << 16);
            pk.y = (unsigned)f2bf(o2) | ((unsigned)f2bf(o3) << 16);
            *(uint2*)(Cb + (size_t)seg * (N_NODES * DIM) + (size_t)m * 256 + nn) = pk;
          }
        } else {
          if (WF32) {
            float4 w; w.x = o0; w.y = o1; w.z = o2; w.w = o3;
            *(float4*)(C + (size_t)m * ldc + n0) = w;
          }
          if (WB16) {
            uint2 pk;
            pk.x = (unsigned)f2bf(o0) | ((unsigned)f2bf(o1) << 16);
            pk.y = (unsigned)f2bf(o2) | ((unsigned)f2bf(o3) << 16);
            *(uint2*)(Cb + (size_t)m * ldcb + n0) = pk;
          }
        }
      }
    }
  }
}

// ---------- agg: one 64-thread block (1 wave) per dst node (r10 config) ----------
// r11's 4-wave packing regressed (+5us): block slot held for max-of-4
// Poisson(32) degrees (~25% imbalance tax) and 4x coarser scheduling.
// Reverted to the measured-best 1-wave-per-block form.
__global__ __launch_bounds__(64) void agg_fused_kernel(
    const unsigned* __restrict__ cnt, const uint2* __restrict__ es_csr,
    const unsigned short* __restrict__ qb,
    const unsigned short* __restrict__ kb, const unsigned short* __restrict__ vb,
    const float* __restrict__ sbuf,
    const float* __restrict__ g, const float* __restrict__ b,
    float* __restrict__ out, unsigned short* __restrict__ outb) {
  const int node = blockIdx.x;
  const int lane = threadIdx.x;
  const int grp = lane >> 4;   // 0..3
  const int t = lane & 15;     // 16-elem chunk index
  const int start = node * BCAP;
  const int deg = min((int)cnt[node], BCAP);
  const int end = start + deg;

  const uint4 qA = *(const uint4*)(qb + (size_t)node * 256 + t * 16);
  const uint4 qB = *(const uint4*)(qb + (size_t)node * 256 + t * 16 + 8);
  float qf[16];
  qf[0] = bf_lo(qA.x);  qf[1] = bf_hi(qA.x);
  qf[2] = bf_lo(qA.y);  qf[3] = bf_hi(qA.y);
  qf[4] = bf_lo(qA.z);  qf[5] = bf_hi(qA.z);
  qf[6] = bf_lo(qA.w);  qf[7] = bf_hi(qA.w);
  qf[8] = bf_lo(qB.x);  qf[9] = bf_hi(qB.x);
  qf[10] = bf_lo(qB.y); qf[11] = bf_hi(qB.y);
  qf[12] = bf_lo(qB.z); qf[13] = bf_hi(qB.z);
  qf[14] = bf_lo(qB.w); qf[15] = bf_hi(qB.w);

  float m = -3.4e38f, dsum = 0.f;
  float a0 = 0.f, a1 = 0.f, a2 = 0.f, a3 = 0.f;

  int ea = start + grp * 2;
  int eb_ = ea + 1;
  bool va = ea < end, vbd = eb_ < end;
  int sa = 0, sb = 0;
  float ba = 0.f, bb = 0.f;
  if (va) { const uint2 es = es_csr[ea]; sa = (int)es.x; ba = __uint_as_float(es.y); }
  if (vbd) { const uint2 es = es_csr[eb_]; sb = (int)es.x; bb = __uint_as_float(es.y); }
  uint4 kAa = *(const uint4*)(kb + (size_t)sa * 256 + t * 16);
  uint4 kBa = *(const uint4*)(kb + (size_t)sa * 256 + t * 16 + 8);
  uint4 kAb = *(const uint4*)(kb + (size_t)sb * 256 + t * 16);
  uint4 kBb = *(const uint4*)(kb + (size_t)sb * 256 + t * 16 + 8);

  for (int base = start; base < end; base += 8) {
    const int s0 = __shfl(sa, 0), s1 = __shfl(sa, 16);
    const int s2 = __shfl(sa, 32), s3 = __shfl(sa, 48);
    const int s4 = __shfl(sb, 0), s5 = __shfl(sb, 16);
    const int s6 = __shfl(sb, 32), s7 = __shfl(sb, 48);
    const uint2 v0 = *(const uint2*)(vb + (size_t)s0 * 256 + lane * 4);
    const uint2 v1 = *(const uint2*)(vb + (size_t)s1 * 256 + lane * 4);
    const uint2 v2 = *(const uint2*)(vb + (size_t)s2 * 256 + lane * 4);
    const uint2 v3 = *(const uint2*)(vb + (size_t)s3 * 256 + lane * 4);
    const uint2 v4 = *(const uint2*)(vb + (size_t)s4 * 256 + lane * 4);
    const uint2 v5 = *(const uint2*)(vb + (size_t)s5 * 256 + lane * 4);
    const uint2 v6 = *(const uint2*)(vb + (size_t)s6 * 256 + lane * 4);
    const uint2 v7 = *(const uint2*)(vb + (size_t)s7 * 256 + lane * 4);

    const int na = base + 8 + grp * 2;
    const int nb = na + 1;
    const bool va_n = na < end, vb_n = nb < end;
    int sa_n = 0, sb_n = 0;
    float ba_n = 0.f, bb_n = 0.f;
    if (va_n) { const uint2 es = es_csr[na]; sa_n = (int)es.x; ba_n = __uint_as_float(es.y); }
    if (vb_n) { const uint2 es = es_csr[nb]; sb_n = (int)es.x; bb_n = __uint_as_float(es.y); }

    float da = qf[0] * bf_lo(kAa.x);
    float db = qf[0] * bf_lo(kAb.x);
    da = fmaf(qf[1], bf_hi(kAa.x), da);  db = fmaf(qf[1], bf_hi(kAb.x), db);
    da = fmaf(qf[2], bf_lo(kAa.y), da);  db = fmaf(qf[2], bf_lo(kAb.y), db);
    da = fmaf(qf[3], bf_hi(kAa.y), da);  db = fmaf(qf[3], bf_hi(kAb.y), db);
    da = fmaf(qf[4], bf_lo(kAa.z), da);  db = fmaf(qf[4], bf_lo(kAb.z), db);
    da = fmaf(qf[5], bf_hi(kAa.z), da);  db = fmaf(qf[5], bf_hi(kAb.z), db);
    da = fmaf(qf[6], bf_lo(kAa.w), da);  db = fmaf(qf[6], bf_lo(kAb.w), db);
    da = fmaf(qf[7], bf_hi(kAa.w), da);  db = fmaf(qf[7], bf_hi(kAb.w), db);
    da = fmaf(qf[8], bf_lo(kBa.x), da);  db = fmaf(qf[8], bf_lo(kBb.x), db);
    da = fmaf(qf[9], bf_hi(kBa.x), da);  db = fmaf(qf[9], bf_hi(kBb.x), db);
    da = fmaf(qf[10], bf_lo(kBa.y), da); db = fmaf(qf[10], bf_lo(kBb.y), db);
    da = fmaf(qf[11], bf_hi(kBa.y), da); db = fmaf(qf[11], bf_hi(kBb.y), db);
    da = fmaf(qf[12], bf_lo(kBa.z), da); db = fmaf(qf[12], bf_lo(kBb.z), db);
    da = fmaf(qf[13], bf_hi(kBa.z), da); db = fmaf(qf[13], bf_hi(kBb.z), db);
    da = fmaf(qf[14], bf_lo(kBa.w), da); db = fmaf(qf[14], bf_lo(kBb.w), db);
    da = fmaf(qf[15], bf_hi(kBa.w), da); db = fmaf(qf[15], bf_hi(kBb.w), db);
    da += __shfl_xor(da, 1);  db += __shfl_xor(db, 1);
    da += __shfl_xor(da, 2);  db += __shfl_xor(db, 2);
    da += __shfl_xor(da, 4);  db += __shfl_xor(db, 4);
    da += __shfl_xor(da, 8);  db += __shfl_xor(db, 8);
    const float sca = va ? fmaf(da, 0.0625f, ba) : -3.4e38f;
    const float scb = vbd ? fmaf(db, 0.0625f, bb) : -3.4e38f;

    const uint4 kAa_n = *(const uint4*)(kb + (size_t)sa_n * 256 + t * 16);
    const uint4 kBa_n = *(const uint4*)(kb + (size_t)sa_n * 256 + t * 16 + 8);
    const uint4 kAb_n = *(const uint4*)(kb + (size_t)sb_n * 256 + t * 16);
    const uint4 kBb_n = *(const uint4*)(kb + (size_t)sb_n * 256 + t * 16 + 8);

    const float c0 = __shfl(sca, 0), c1 = __shfl(sca, 16);
    const float c2 = __shfl(sca, 32), c3 = __shfl(sca, 48);
    const float c4 = __shfl(scb, 0), c5 = __shfl(scb, 16);
    const float c6 = __shfl(scb, 32), c7 = __shfl(scb, 48);

    const float mx = fmaxf(fmaxf(fmaxf(c0, c1), fmaxf(c2, c3)),
                           fmaxf(fmaxf(c4, c5), fmaxf(c6, c7)));
    const float mn = fmaxf(m, mx);
    const float scale = __expf(m - mn);
    const float w0 = __expf(c0 - mn), w1 = __expf(c1 - mn);
    const float w2 = __expf(c2 - mn), w3 = __expf(c3 - mn);
    const float w4 = __expf(c4 - mn), w5 = __expf(c5 - mn);
    const float w6 = __expf(c6 - mn), w7 = __expf(c7 - mn);
    dsum = fmaf(dsum, scale, ((w0 + w1) + (w2 + w3)) + ((w4 + w5) + (w6 + w7)));

    float t0 = a0 * scale;
    t0 = fmaf(w0, bf_lo(v0.x), t0); t0 = fmaf(w1, bf_lo(v1.x), t0);
    t0 = fmaf(w2, bf_lo(v2.x), t0); t0 = fmaf(w3, bf_lo(v3.x), t0);
    t0 = fmaf(w4, bf_lo(v4.x), t0); t0 = fmaf(w5, bf_lo(v5.x), t0);
    t0 = fmaf(w6, bf_lo(v6.x), t0); t0 = fmaf(w7, bf_lo(v7.x), t0);
    a0 = t0;
    float t1 = a1 * scale;
    t1 = fmaf(w0, bf_hi(v0.x), t1); t1 = fmaf(w1, bf_hi(v1.x), t1);
    t1 = fmaf(w2, bf_hi(v2.x), t1); t1 = fmaf(w3, bf_hi(v3.x), t1);
    t1 = fmaf(w4, bf_hi(v4.x), t1); t1 = fmaf(w5, bf_hi(v5.x), t1);
    t1 = fmaf(w6, bf_hi(v6.x), t1); t1 = fmaf(w7, bf_hi(v7.x), t1);
    a1 = t1;
    float t2 = a2 * scale;
    t2 = fmaf(w0, bf_lo(v0.y), t2); t2 = fmaf(w1, bf_lo(v1.y), t2);
    t2 = fmaf(w2, bf_lo(v2.y), t2); t2 = fmaf(w3, bf_lo(v3.y), t2);
    t2 = fmaf(w4, bf_lo(v4.y), t2); t2 = fmaf(w5, bf_lo(v5.y), t2);
    t2 = fmaf(w6, bf_lo(v6.y), t2); t2 = fmaf(w7, bf_lo(v7.y), t2);
    a2 = t2;
    float t3 = a3 * scale;
    t3 = fmaf(w0, bf_hi(v0.y), t3); t3 = fmaf(w1, bf_hi(v1.y), t3);
    t3 = fmaf(w2, bf_hi(v2.y), t3); t3 = fmaf(w3, bf_hi(v3.y), t3);
    t3 = fmaf(w4, bf_hi(v4.y), t3); t3 = fmaf(w5, bf_hi(v5.y), t3);
    t3 = fmaf(w6, bf_hi(v6.y), t3); t3 = fmaf(w7, bf_hi(v7.y), t3);
    a3 = t3;
    m = mn;

    sa = sa_n; sb = sb_n;
    ba = ba_n; bb = bb_n;
    va = va_n; vbd = vb_n;
    kAa = kAa_n; kBa = kBa_n;
    kAb = kAb_n; kBb = kBb_n;
  }
  const float inv = 1.0f / fmaxf(dsum, 1e-12f);

  const float4 sv = *(const float4*)(sbuf + (size_t)node * 256 + lane * 4);
  float r0 = a0 * inv + sv.x;
  float r1 = a1 * inv + sv.y;
  float r2 = a2 * inv + sv.z;
  float r3 = a3 * inv + sv.w;

  float sum = r0 + r1 + r2 + r3;
#pragma unroll
  for (int off = 32; off > 0; off >>= 1) sum += __shfl_xor(sum, off);
  const float mu = sum * (1.0f / 256.0f);
  const float d0 = r0 - mu, d1 = r1 - mu, d2 = r2 - mu, d3 = r3 - mu;
  float vs = d0 * d0 + d1 * d1 + d2 * d2 + d3 * d3;
#pragma unroll
  for (int off = 32; off > 0; off >>= 1) vs += __shfl_xor(vs, off);
  const float rs = rsqrtf(vs * (1.0f / 256.0f) + 1e-5f);

  const float4 gv = *(const float4*)(g + lane * 4);
  const float4 bv = *(const float4*)(b + lane * 4);
  float4 o;
  o.x = d0 * rs * gv.x + bv.x;
  o.y = d1 * rs * gv.y + bv.y;
  o.z = d2 * rs * gv.z + bv.z;
  o.w = d3 * rs * gv.w + bv.w;
  *(float4*)(out + (size_t)node * 256 + lane * 4) = o;
  uint2 pk;
  pk.x = (unsigned)f2bf(o.x) | ((unsigned)f2bf(o.y) << 16);
  pk.y = (unsigned)f2bf(o.z) | ((unsigned)f2bf(o.w) << 16);
  *(uint2*)(outb + (size_t)node * 256 + lane * 4) = pk;
}

// ---------- LN2 ----------

__global__ __launch_bounds__(256) void ln2_kernel(
    const float* __restrict__ x1, const float* __restrict__ y,
    const float* __restrict__ g, const float* __restrict__ b,
    float* __restrict__ out) {
  __shared__ float red[4];
  const int row = blockIdx.x;
  const int t = threadIdx.x;
  float v = x1[(size_t)row * 256 + t] + y[(size_t)row * 256 + t];
  float s = v;
#pragma unroll
  for (int off = 32; off > 0; off >>= 1) s += __shfl_xor(s, off);
  if ((t & 63) == 0) red[t >> 6] = s;
  __syncthreads();
  float tot = red[0] + red[1] + red[2] + red[3];
  __syncthreads();
  const float mu = tot * (1.0f / 256.0f);
  const float d = v - mu;
  float vs = d * d;
#pragma unroll
  for (int off = 32; off > 0; off >>= 1) vs += __shfl_xor(vs, off);
  if ((t & 63) == 0) red[t >> 6] = vs;
  __syncthreads();
  float vtot = red[0] + red[1] + red[2] + red[3];
  const float r = rsqrtf(vtot * (1.0f / 256.0f) + 1e-5f);
  out[(size_t)row * 256 + t] = d * r * g[t] + b[t];
}

// ---------- launch ----------

extern "C" void kernel_launch(void* const* d_in, const int* in_sizes, int n_in,
                              void* d_out, int out_size, void* d_ws,
                              size_t ws_size, hipStream_t stream) {
  const float* x = (const float*)d_in[0];
  const int* ei = (const int*)d_in[1];
  const float* ew = (const float*)d_in[2];
  const float* wq = (const float*)d_in[3];
  const float* bq = (const float*)d_in[4];
  const float* wk = (const float*)d_in[5];
  const float* bk = (const float*)d_in[6];
  const float* wv = (const float*)d_in[7];
  const float* bv = (const float*)d_in[8];
  const float* wsm = (const float*)d_in[9];
  const float* bs = (const float*)d_in[10];
  const float* we = (const float*)d_in[11];
  const float* be = (const float*)d_in[12];
  const float* g1 = (const float*)d_in[13];
  const float* b1 = (const float*)d_in[14];
  const float* g2 = (const float*)d_in[15];
  const float* b2 = (const float*)d_in[16];
  const float* wff1 = (const float*)d_in[17];
  const float* bff1 = (const float*)d_in[18];
  const float* wff2 = (const float*)d_in[19];
  const float* bff2 = (const float*)d_in[20];
  float* out = (float*)d_out;

  unsigned short* qb = (unsigned short*)d_ws;        // 3 * N*256 bf16 (q,k,v)
  unsigned short* kbp = qb + 2560000;
  unsigned short* vbp = qb + 5120000;
  float* sbuf = (float*)(qb + 7680000);              // N*256 f32 (x + skip)
  uint2* es_csr = (uint2*)(sbuf + 2560000);          // N*BCAP x {src, eb}
  unsigned* cnt = (unsigned*)(es_csr + (size_t)N_NODES * BCAP);  // N
  float* x1 = (float*)(cnt + N_NODES);               // N*256
  float* y = x1 + 2560000;                           // N*256
  unsigned short* x1b = (unsigned short*)(y + 2560000);  // N*256 bf16
  unsigned short* h_b = x1b + 2560000;               // N*512 bf16
  unsigned short* xb = h_b;                          // alias (xb dead before h_b written)
  unsigned short* wt_qkvs = h_b + 5120000;           // 262144
  unsigned short* wt_ff1 = wt_qkvs + 262144;         // 131072
  unsigned short* wt_ff2 = wt_ff1 + 131072;          // 131072
  float* bias_qkvs = (float*)(wt_ff2 + 131072);      // 1024
  unsigned* pcnt = (unsigned*)(bias_qkvs + 1024);    // 256 (partition counters)
  uint2* pbuf = (uint2*)(pcnt + 256);                // P_PARTS*PCAP records (4MB)

  dim3 blk(256);
  const int mb = (N_NODES + 63) / 64;  // 157

  // zero partition counters, then merged prep + scatter-p1 (overlap in one launch)
  hipMemsetAsync(pcnt, 0, P_PARTS * sizeof(unsigned), stream);
  prep_p1_kernel<<<P1_BLOCKS + PREP_TOTAL / 256, blk, 0, stream>>>(
      wq, wk, wv, wsm, bq, bk, bv, bs, wff1, wff2, x,
      wt_qkvs, bias_qkvs, wt_ff1, wt_ff2, xb,
      ei, ew, we, be, pcnt, pbuf);

  // q,k,v (bf16) + sbuf = x + x@ws + bs (f32), scatter pass-2 fused as the
  // first 250 blocks of the flattened grid (overlaps with GEMM)
  mfma_gemm<0, 0, 0, 1><<<dim3(P_PARTS + 16 * mb), blk, 0, stream>>>(
      xb, 256, wt_qkvs, bias_qkvs, x, sbuf, 0, qb, 0, N_NODES, 256,
      pcnt, pbuf, cnt, es_csr);

  agg_fused_kernel<<<dim3(N_NODES), dim3(64), 0, stream>>>(
      cnt, es_csr, qb, kbp, vbp, sbuf, g1, b1, x1, x1b);

  // h = gelu(x1 @ wff1 + bff1) (bf16)  [64^2 tile, (8,157)]
  mfma_gemm<1, 0, 1, 0><<<dim3(8, mb), blk, 0, stream>>>(
      x1b, 256, wt_ff1, bff1, nullptr, (float*)nullptr, 0, h_b, 512, N_NODES, 256,
      nullptr, nullptr, nullptr, nullptr);

  // y = h @ wff2 + bff2 (f32)  [64^2 tile, (4,157)]
  mfma_gemm<0, 1, 0, 0><<<dim3(4, mb), blk, 0, stream>>>(
      h_b, 512, wt_ff2, bff2, nullptr, y, 256, (unsigned short*)nullptr, 0, N_NODES, 512,
      nullptr, nullptr, nullptr, nullptr);

  ln2_kernel<<<N_NODES, blk, 0, stream>>>(x1, y, g2, b2, out);
}

// Round 13
// 117.555 us; speedup vs baseline: 1.0448x; 1.0376x over previous
//
#include <hip/hip_runtime.h>
#include <math.h>

#define N_NODES 10000
#define N_EDGES 320000
#define DIM 256
#define BCAP 128   // edge bucket capacity per node (Poisson(32): P(>128) ~ 1e-40)

// edge partition sort parameters
#define P_PARTS 250   // dst-range partitions
#define NPP 40        // nodes per partition (250*40 = 10000)
#define PCAP 2048     // records per partition (mean 1280, >14 sigma headroom)
#define EPT 4         // edges per thread in pass 1 (157 blocks @ 512 thr)

typedef __attribute__((ext_vector_type(8))) short bf16x8;
typedef __attribute__((ext_vector_type(4))) float fx4;

typedef __attribute__((address_space(3))) unsigned lds_u32;
typedef __attribute__((address_space(1))) const unsigned gbl_u32;

// ---------- helpers ----------

__device__ __forceinline__ float gelu_tanh(float x) {
  const float k0 = 0.7978845608028654f;  // sqrt(2/pi)
  float x3 = x * x * x;
  return 0.5f * x * (1.0f + tanhf(k0 * (x + 0.044715f * x3)));
}

__device__ __forceinline__ unsigned short f2bf(float f) {
  unsigned u = __float_as_uint(f);
  unsigned r = 0x7FFFu + ((u >> 16) & 1u);
  return (unsigned short)((u + r) >> 16);
}

__device__ __forceinline__ float bf_lo(unsigned u) { return __uint_as_float(u << 16); }
__device__ __forceinline__ float bf_hi(unsigned u) { return __uint_as_float(u & 0xFFFF0000u); }

// ---------- merged prep: weights->bf16^T, bias concat, x->bf16, pcnt zero ----------
// (r10-verified config: prep separate from p1; r12 showed the prep+p1 fusion
//  plus memsetAsync cost ~4us, not saved it.)

#define SEG_QKVS 262144
#define SEG_FF1 131072
#define SEG_FF2 131072
#define SEG_BIAS 1024
#define SEG_CONV 320000   // N*D/8
#define SEG_ZCNT 256      // partition counters
#define PREP_TOTAL (SEG_QKVS + SEG_FF1 + SEG_FF2 + SEG_BIAS + SEG_CONV + SEG_ZCNT)

__global__ __launch_bounds__(256) void prep_all_kernel(
    const float* __restrict__ wq, const float* __restrict__ wk,
    const float* __restrict__ wv, const float* __restrict__ ws,
    const float* __restrict__ bq, const float* __restrict__ bk,
    const float* __restrict__ bv, const float* __restrict__ bs,
    const float* __restrict__ wff1, const float* __restrict__ wff2,
    const float* __restrict__ x,
    unsigned short* __restrict__ wt_qkvs, float* __restrict__ bias_qkvs,
    unsigned short* __restrict__ wt_ff1, unsigned short* __restrict__ wt_ff2,
    unsigned short* __restrict__ xb, unsigned* __restrict__ pcnt) {
  int id = blockIdx.x * 256 + threadIdx.x;
  if (id < SEG_QKVS) {  // qkvs: [1024][256]
    const int n = id >> 8, k = id & 255;
    const float* w = (n < 256) ? wq : (n < 512) ? wk : (n < 768) ? wv : ws;
    wt_qkvs[id] = f2bf(w[k * 256 + (n & 255)]);
    return;
  }
  id -= SEG_QKVS;
  if (id < SEG_FF1) {  // ff1: [512][256]
    const int n = id >> 8, k = id & 255;
    wt_ff1[id] = f2bf(wff1[k * 512 + n]);
    return;
  }
  id -= SEG_FF1;
  if (id < SEG_FF2) {  // ff2: [256][512]
    const int n = id >> 9, k = id & 511;
    wt_ff2[id] = f2bf(wff2[k * 256 + n]);
    return;
  }
  id -= SEG_FF2;
  if (id < SEG_BIAS) {
    bias_qkvs[id] = (id < 256) ? bq[id] : (id < 512) ? bk[id & 255]
                    : (id < 768) ? bv[id & 255] : bs[id & 255];
    return;
  }
  id -= SEG_BIAS;
  if (id < SEG_CONV) {
    const int base = id * 8;
    float4 a = *(const float4*)(x + base);
    float4 b = *(const float4*)(x + base + 4);
    unsigned short h[8] = {f2bf(a.x), f2bf(a.y), f2bf(a.z), f2bf(a.w),
                           f2bf(b.x), f2bf(b.y), f2bf(b.z), f2bf(b.w)};
    *(uint4*)(xb + base) = *(const uint4*)h;
    return;
  }
  id -= SEG_CONV;
  if (id < SEG_ZCNT) pcnt[id] = 0u;
}

// ---------- edge scatter pass 1: partition by dst range ----------
__global__ __launch_bounds__(512) void scatter_p1(
    const int* __restrict__ ei, const float* __restrict__ ew,
    const float* __restrict__ we, const float* __restrict__ be,
    unsigned* __restrict__ pcnt, uint2* __restrict__ pbuf) {
  __shared__ unsigned lcnt[P_PARTS];
  __shared__ unsigned lbase[P_PARTS];
  const int tid = threadIdx.x;
  for (int i = tid; i < P_PARTS; i += 512) lcnt[i] = 0;
  __syncthreads();
  const float wes = we[0], bes = be[0];
  const int e0 = blockIdx.x * (512 * EPT);

  unsigned pp[EPT];
  unsigned rr[EPT];
  unsigned sv[EPT];
  float ebv[EPT];
#pragma unroll
  for (int j = 0; j < EPT; j++) {
    const int e = e0 + j * 512 + tid;
    pp[j] = 0;
    rr[j] = 0xFFFFFFFFu;
    if (e < N_EDGES) {
      const int dst = ei[N_EDGES + e];
      const int src = ei[e];
      const int p = dst / NPP;
      sv[j] = (unsigned)dst | ((unsigned)src << 16);
      ebv[j] = fmaf(ew[e], wes, bes);
      pp[j] = (unsigned)p;
      rr[j] = atomicAdd(&lcnt[p], 1u);
    }
  }
  __syncthreads();
  for (int i = tid; i < P_PARTS; i += 512) {
    const unsigned c = lcnt[i];
    lbase[i] = c ? atomicAdd(&pcnt[i], c) : 0u;
  }
  __syncthreads();
#pragma unroll
  for (int j = 0; j < EPT; j++) {
    if (rr[j] != 0xFFFFFFFFu) {
      const unsigned pos = lbase[pp[j]] + rr[j];
      if (pos < PCAP) {
        uint2 rec;
        rec.x = sv[j];
        rec.y = __float_as_uint(ebv[j]);
        pbuf[(size_t)pp[j] * PCAP + pos] = rec;
      }
    }
  }
}

// ---------- bf16 MFMA GEMM, 64x64 tile (r3-verified; r10 +p2-fusion) ----------
// Async global_load_lds staging, dbuf, counted vmcnt(4), swapped-operand C^T
// epilogue. SPLIT launches a flattened grid of P_PARTS + 2512 blocks: the
// first 250 run scatter pass-2 (pbuf->es_csr/cnt, disjoint from GEMM work)
// so it overlaps instead of serializing (measured r10: -7.6us total).
template <int GELU, int WF32, int WB16, int SPLIT>
__global__ __launch_bounds__(256) void mfma_gemm(
    const unsigned short* __restrict__ A, int lda,
    const unsigned short* __restrict__ Bt,
    const float* __restrict__ bias,
    const float* __restrict__ xres,
    float* __restrict__ C, int ldc,
    unsigned short* __restrict__ Cb, int ldcb,
    int M, int K,
    const unsigned* __restrict__ pcnt, const uint2* __restrict__ pbuf,
    unsigned* __restrict__ cnt, uint2* __restrict__ es_csr) {
  __shared__ char lds[32768];  // 2 buffers x (A 8KB + B 8KB); p2 aliases 160B
  const int tid = threadIdx.x;

  if (SPLIT) {
    const int bid = blockIdx.x;
    if (bid < P_PARTS) {
      // fused scatter pass 2
      unsigned* lcnt = (unsigned*)lds;
      if (tid < NPP) lcnt[tid] = 0;
      __syncthreads();
      const int n0 = bid * NPP;
      const int tot = min((int)pcnt[bid], PCAP);
      for (int i = tid; i < tot; i += 256) {
        const uint2 rec = pbuf[(size_t)bid * PCAP + i];
        const int dst = (int)(rec.x & 0xFFFFu);
        const int src = (int)(rec.x >> 16);
        const unsigned r = atomicAdd(&lcnt[dst - n0], 1u);
        if (r < BCAP) {
          uint2 o;
          o.x = (unsigned)src;
          o.y = rec.y;
          es_csr[(size_t)dst * BCAP + r] = o;
        }
      }
      __syncthreads();
      if (tid < NPP) cnt[n0 + tid] = lcnt[tid];
      return;
    }
  }

  const int l = tid & 63;
  const int wid = tid >> 6;
  const int wrow = (wid & 1) * 32;
  const int wcol = (wid >> 1) * 32;
  int bm, bn;
  if (SPLIT) {
    const int bid2 = blockIdx.x - P_PARTS;   // 0..2511
    bm = (bid2 >> 4) * 64;                   // 157 row strips
    bn = (bid2 & 15) * 64;                   // 16 col strips (N=1024)
  } else {
    bm = blockIdx.y * 64;
    bn = blockIdx.x * 64;
  }

  fx4 acc[2][2];
#pragma unroll
  for (int i = 0; i < 2; i++)
#pragma unroll
    for (int j = 0; j < 2; j++) acc[i][j] = (fx4)(0.0f);

#define STAGE(BUFOFF, KB)                                                      \
  {                                                                            \
    _Pragma("unroll") for (int i = 0; i < 2; i++) {                            \
      const int id = i * 256 + tid;                                            \
      const int row = id >> 3;                                                 \
      const int ccs = (id & 7) ^ (row & 7);                                    \
      __builtin_amdgcn_global_load_lds(                                        \
          (gbl_u32*)(A + (size_t)(bm + row) * lda + (KB) + ccs * 8),           \
          (lds_u32*)(lds + (BUFOFF) + id * 16), 16, 0, 0);                     \
    }                                                                          \
    _Pragma("unroll") for (int i = 0; i < 2; i++) {                            \
      const int id = i * 256 + tid;                                            \
      const int row = id >> 3;                                                 \
      const int ccs = (id & 7) ^ (row & 7);                                    \
      __builtin_amdgcn_global_load_lds(                                        \
          (gbl_u32*)(Bt + (size_t)(bn + row) * K + (KB) + ccs * 8),            \
          (lds_u32*)(lds + (BUFOFF) + 8192 + id * 16), 16, 0, 0);              \
    }                                                                          \
  }

  STAGE(0, 0);

  unsigned cur = 0;
  for (int kb = 0; kb < K; kb += 64) {
    if (kb + 64 < K) {
      STAGE((cur ^ 1) * 16384, kb + 64);
      asm volatile("s_waitcnt vmcnt(4)" ::: "memory");
    } else {
      asm volatile("s_waitcnt vmcnt(0)" ::: "memory");
    }
    __builtin_amdgcn_s_barrier();
    __builtin_amdgcn_sched_barrier(0);

    const char* As = lds + cur * 16384;
    const char* Bs = As + 8192;
#pragma unroll
    for (int kk = 0; kk < 2; kk++) {
      const int kbyte = (kk * 64 + ((l >> 4) << 4)) ^ ((l & 7) << 4);
      bf16x8 af[2], bg[2];
#pragma unroll
      for (int f = 0; f < 2; f++) {
        const int ar = wrow + f * 16 + (l & 15);
        af[f] = *(const bf16x8*)(As + ar * 128 + kbyte);
        const int br = wcol + f * 16 + (l & 15);
        bg[f] = *(const bf16x8*)(Bs + br * 128 + kbyte);
      }
      // operands swapped -> C^T fragment (thread holds 4 consecutive n)
#pragma unroll
      for (int fr = 0; fr < 2; fr++)
#pragma unroll
        for (int fc = 0; fc < 2; fc++)
          acc[fr][fc] = __builtin_amdgcn_mfma_f32_16x16x32_bf16(
              bg[fc], af[fr], acc[fr][fc], 0, 0, 0);
    }
    __builtin_amdgcn_s_barrier();
    cur ^= 1;
  }
#undef STAGE

  // epilogue (transposed fragments): m fixed per thread, n0..n0+3 in regs
#pragma unroll
  for (int fr = 0; fr < 2; fr++) {
    const int m = bm + wrow + fr * 16 + (l & 15);
    if (m < M) {
#pragma unroll
      for (int fc = 0; fc < 2; fc++) {
        const int n0 = bn + wcol + fc * 16 + ((l >> 4) << 2);
        const float4 b4 = *(const float4*)(bias + n0);
        fx4 v = acc[fr][fc];
        float o0 = v[0] + b4.x;
        float o1 = v[1] + b4.y;
        float o2 = v[2] + b4.z;
        float o3 = v[3] + b4.w;
        if (GELU) {
          o0 = gelu_tanh(o0); o1 = gelu_tanh(o1);
          o2 = gelu_tanh(o2); o3 = gelu_tanh(o3);
        }
        if (SPLIT) {
          const int seg = n0 >> 8, nn = n0 & 255;
          if (seg == 3) {
            const float4 xr = *(const float4*)(xres + (size_t)m * 256 + nn);
            float4 w;
            w.x = o0 + xr.x; w.y = o1 + xr.y; w.z = o2 + xr.z; w.w = o3 + xr.w;
            *(float4*)(C + (size_t)m * 256 + nn) = w;
          } else {
            uint2 pk;
            pk.x = (unsigned)f2bf(o0) | ((unsigned)f2bf(o1) << 16);
            pk.y = (unsigned)f2bf(o2) | ((unsigned)f2bf(o3) << 16);
            *(uint2*)(Cb + (size_t)seg * (N_NODES * DIM) + (size_t)m * 256 + nn) = pk;
          }
        } else {
          if (WF32) {
            float4 w; w.x = o0; w.y = o1; w.z = o2; w.w = o3;
            *(float4*)(C + (size_t)m * ldc + n0) = w;
          }
          if (WB16) {
            uint2 pk;
            pk.x = (unsigned)f2bf(o0) | ((unsigned)f2bf(o1) << 16);
            pk.y = (unsigned)f2bf(o2) | ((unsigned)f2bf(o3) << 16);
            *(uint2*)(Cb + (size_t)m * ldcb + n0) = pk;
          }
        }
      }
    }
  }
}

// ---------- agg: one 64-thread block (1 wave) per dst node ----------
__global__ __launch_bounds__(64) void agg_fused_kernel(
    const unsigned* __restrict__ cnt, const uint2* __restrict__ es_csr,
    const unsigned short* __restrict__ qb,
    const unsigned short* __restrict__ kb, const unsigned short* __restrict__ vb,
    const float* __restrict__ sbuf,
    const float* __restrict__ g, const float* __restrict__ b,
    float* __restrict__ out, unsigned short* __restrict__ outb) {
  const int node = blockIdx.x;
  const int lane = threadIdx.x;
  const int grp = lane >> 4;   // 0..3
  const int t = lane & 15;     // 16-elem chunk index
  const int start = node * BCAP;
  const int deg = min((int)cnt[node], BCAP);
  const int end = start + deg;

  const uint4 qA = *(const uint4*)(qb + (size_t)node * 256 + t * 16);
  const uint4 qB = *(const uint4*)(qb + (size_t)node * 256 + t * 16 + 8);
  float qf[16];
  qf[0] = bf_lo(qA.x);  qf[1] = bf_hi(qA.x);
  qf[2] = bf_lo(qA.y);  qf[3] = bf_hi(qA.y);
  qf[4] = bf_lo(qA.z);  qf[5] = bf_hi(qA.z);
  qf[6] = bf_lo(qA.w);  qf[7] = bf_hi(qA.w);
  qf[8] = bf_lo(qB.x);  qf[9] = bf_hi(qB.x);
  qf[10] = bf_lo(qB.y); qf[11] = bf_hi(qB.y);
  qf[12] = bf_lo(qB.z); qf[13] = bf_hi(qB.z);
  qf[14] = bf_lo(qB.w); qf[15] = bf_hi(qB.w);

  float m = -3.4e38f, dsum = 0.f;
  float a0 = 0.f, a1 = 0.f, a2 = 0.f, a3 = 0.f;

  int ea = start + grp * 2;
  int eb_ = ea + 1;
  bool va = ea < end, vbd = eb_ < end;
  int sa = 0, sb = 0;
  float ba = 0.f, bb = 0.f;
  if (va) { const uint2 es = es_csr[ea]; sa = (int)es.x; ba = __uint_as_float(es.y); }
  if (vbd) { const uint2 es = es_csr[eb_]; sb = (int)es.x; bb = __uint_as_float(es.y); }
  uint4 kAa = *(const uint4*)(kb + (size_t)sa * 256 + t * 16);
  uint4 kBa = *(const uint4*)(kb + (size_t)sa * 256 + t * 16 + 8);
  uint4 kAb = *(const uint4*)(kb + (size_t)sb * 256 + t * 16);
  uint4 kBb = *(const uint4*)(kb + (size_t)sb * 256 + t * 16 + 8);

  for (int base = start; base < end; base += 8) {
    const int s0 = __shfl(sa, 0), s1 = __shfl(sa, 16);
    const int s2 = __shfl(sa, 32), s3 = __shfl(sa, 48);
    const int s4 = __shfl(sb, 0), s5 = __shfl(sb, 16);
    const int s6 = __shfl(sb, 32), s7 = __shfl(sb, 48);
    const uint2 v0 = *(const uint2*)(vb + (size_t)s0 * 256 + lane * 4);
    const uint2 v1 = *(const uint2*)(vb + (size_t)s1 * 256 + lane * 4);
    const uint2 v2 = *(const uint2*)(vb + (size_t)s2 * 256 + lane * 4);
    const uint2 v3 = *(const uint2*)(vb + (size_t)s3 * 256 + lane * 4);
    const uint2 v4 = *(const uint2*)(vb + (size_t)s4 * 256 + lane * 4);
    const uint2 v5 = *(const uint2*)(vb + (size_t)s5 * 256 + lane * 4);
    const uint2 v6 = *(const uint2*)(vb + (size_t)s6 * 256 + lane * 4);
    const uint2 v7 = *(const uint2*)(vb + (size_t)s7 * 256 + lane * 4);

    const int na = base + 8 + grp * 2;
    const int nb = na + 1;
    const bool va_n = na < end, vb_n = nb < end;
    int sa_n = 0, sb_n = 0;
    float ba_n = 0.f, bb_n = 0.f;
    if (va_n) { const uint2 es = es_csr[na]; sa_n = (int)es.x; ba_n = __uint_as_float(es.y); }
    if (vb_n) { const uint2 es = es_csr[nb]; sb_n = (int)es.x; bb_n = __uint_as_float(es.y); }

    float da = qf[0] * bf_lo(kAa.x);
    float db = qf[0] * bf_lo(kAb.x);
    da = fmaf(qf[1], bf_hi(kAa.x), da);  db = fmaf(qf[1], bf_hi(kAb.x), db);
    da = fmaf(qf[2], bf_lo(kAa.y), da);  db = fmaf(qf[2], bf_lo(kAb.y), db);
    da = fmaf(qf[3], bf_hi(kAa.y), da);  db = fmaf(qf[3], bf_hi(kAb.y), db);
    da = fmaf(qf[4], bf_lo(kAa.z), da);  db = fmaf(qf[4], bf_lo(kAb.z), db);
    da = fmaf(qf[5], bf_hi(kAa.z), da);  db = fmaf(qf[5], bf_hi(kAb.z), db);
    da = fmaf(qf[6], bf_lo(kAa.w), da);  db = fmaf(qf[6], bf_lo(kAb.w), db);
    da = fmaf(qf[7], bf_hi(kAa.w), da);  db = fmaf(qf[7], bf_hi(kAb.w), db);
    da = fmaf(qf[8], bf_lo(kBa.x), da);  db = fmaf(qf[8], bf_lo(kBb.x), db);
    da = fmaf(qf[9], bf_hi(kBa.x), da);  db = fmaf(qf[9], bf_hi(kBb.x), db);
    da = fmaf(qf[10], bf_lo(kBa.y), da); db = fmaf(qf[10], bf_lo(kBb.y), db);
    da = fmaf(qf[11], bf_hi(kBa.y), da); db = fmaf(qf[11], bf_hi(kBb.y), db);
    da = fmaf(qf[12], bf_lo(kBa.z), da); db = fmaf(qf[12], bf_lo(kBb.z), db);
    da = fmaf(qf[13], bf_hi(kBa.z), da); db = fmaf(qf[13], bf_hi(kBb.z), db);
    da = fmaf(qf[14], bf_lo(kBa.w), da); db = fmaf(qf[14], bf_lo(kBb.w), db);
    da = fmaf(qf[15], bf_hi(kBa.w), da); db = fmaf(qf[15], bf_hi(kBb.w), db);
    da += __shfl_xor(da, 1);  db += __shfl_xor(db, 1);
    da += __shfl_xor(da, 2);  db += __shfl_xor(db, 2);
    da += __shfl_xor(da, 4);  db += __shfl_xor(db, 4);
    da += __shfl_xor(da, 8);  db += __shfl_xor(db, 8);
    const float sca = va ? fmaf(da, 0.0625f, ba) : -3.4e38f;
    const float scb = vbd ? fmaf(db, 0.0625f, bb) : -3.4e38f;

    const uint4 kAa_n = *(const uint4*)(kb + (size_t)sa_n * 256 + t * 16);
    const uint4 kBa_n = *(const uint4*)(kb + (size_t)sa_n * 256 + t * 16 + 8);
    const uint4 kAb_n = *(const uint4*)(kb + (size_t)sb_n * 256 + t * 16);
    const uint4 kBb_n = *(const uint4*)(kb + (size_t)sb_n * 256 + t * 16 + 8);

    const float c0 = __shfl(sca, 0), c1 = __shfl(sca, 16);
    const float c2 = __shfl(sca, 32), c3 = __shfl(sca, 48);
    const float c4 = __shfl(scb, 0), c5 = __shfl(scb, 16);
    const float c6 = __shfl(scb, 32), c7 = __shfl(scb, 48);

    const float mx = fmaxf(fmaxf(fmaxf(c0, c1), fmaxf(c2, c3)),
                           fmaxf(fmaxf(c4, c5), fmaxf(c6, c7)));
    const float mn = fmaxf(m, mx);
    const float scale = __expf(m - mn);
    const float w0 = __expf(c0 - mn), w1 = __expf(c1 - mn);
    const float w2 = __expf(c2 - mn), w3 = __expf(c3 - mn);
    const float w4 = __expf(c4 - mn), w5 = __expf(c5 - mn);
    const float w6 = __expf(c6 - mn), w7 = __expf(c7 - mn);
    dsum = fmaf(dsum, scale, ((w0 + w1) + (w2 + w3)) + ((w4 + w5) + (w6 + w7)));

    float t0 = a0 * scale;
    t0 = fmaf(w0, bf_lo(v0.x), t0); t0 = fmaf(w1, bf_lo(v1.x), t0);
    t0 = fmaf(w2, bf_lo(v2.x), t0); t0 = fmaf(w3, bf_lo(v3.x), t0);
    t0 = fmaf(w4, bf_lo(v4.x), t0); t0 = fmaf(w5, bf_lo(v5.x), t0);
    t0 = fmaf(w6, bf_lo(v6.x), t0); t0 = fmaf(w7, bf_lo(v7.x), t0);
    a0 = t0;
    float t1 = a1 * scale;
    t1 = fmaf(w0, bf_hi(v0.x), t1); t1 = fmaf(w1, bf_hi(v1.x), t1);
    t1 = fmaf(w2, bf_hi(v2.x), t1); t1 = fmaf(w3, bf_hi(v3.x), t1);
    t1 = fmaf(w4, bf_hi(v4.x), t1); t1 = fmaf(w5, bf_hi(v5.x), t1);
    t1 = fmaf(w6, bf_hi(v6.x), t1); t1 = fmaf(w7, bf_hi(v7.x), t1);
    a1 = t1;
    float t2 = a2 * scale;
    t2 = fmaf(w0, bf_lo(v0.y), t2); t2 = fmaf(w1, bf_lo(v1.y), t2);
    t2 = fmaf(w2, bf_lo(v2.y), t2); t2 = fmaf(w3, bf_lo(v3.y), t2);
    t2 = fmaf(w4, bf_lo(v4.y), t2); t2 = fmaf(w5, bf_lo(v5.y), t2);
    t2 = fmaf(w6, bf_lo(v6.y), t2); t2 = fmaf(w7, bf_lo(v7.y), t2);
    a2 = t2;
    float t3 = a3 * scale;
    t3 = fmaf(w0, bf_hi(v0.y), t3); t3 = fmaf(w1, bf_hi(v1.y), t3);
    t3 = fmaf(w2, bf_hi(v2.y), t3); t3 = fmaf(w3, bf_hi(v3.y), t3);
    t3 = fmaf(w4, bf_hi(v4.y), t3); t3 = fmaf(w5, bf_hi(v5.y), t3);
    t3 = fmaf(w6, bf_hi(v6.y), t3); t3 = fmaf(w7, bf_hi(v7.y), t3);
    a3 = t3;
    m = mn;

    sa = sa_n; sb = sb_n;
    ba = ba_n; bb = bb_n;
    va = va_n; vbd = vb_n;
    kAa = kAa_n; kBa = kBa_n;
    kAb = kAb_n; kBb = kBb_n;
  }
  const float inv = 1.0f / fmaxf(dsum, 1e-12f);

  const float4 sv = *(const float4*)(sbuf + (size_t)node * 256 + lane * 4);
  float r0 = a0 * inv + sv.x;
  float r1 = a1 * inv + sv.y;
  float r2 = a2 * inv + sv.z;
  float r3 = a3 * inv + sv.w;

  float sum = r0 + r1 + r2 + r3;
#pragma unroll
  for (int off = 32; off > 0; off >>= 1) sum += __shfl_xor(sum, off);
  const float mu = sum * (1.0f / 256.0f);
  const float d0 = r0 - mu, d1 = r1 - mu, d2 = r2 - mu, d3 = r3 - mu;
  float vs = d0 * d0 + d1 * d1 + d2 * d2 + d3 * d3;
#pragma unroll
  for (int off = 32; off > 0; off >>= 1) vs += __shfl_xor(vs, off);
  const float rs = rsqrtf(vs * (1.0f / 256.0f) + 1e-5f);

  const float4 gv = *(const float4*)(g + lane * 4);
  const float4 bv = *(const float4*)(b + lane * 4);
  float4 o;
  o.x = d0 * rs * gv.x + bv.x;
  o.y = d1 * rs * gv.y + bv.y;
  o.z = d2 * rs * gv.z + bv.z;
  o.w = d3 * rs * gv.w + bv.w;
  *(float4*)(out + (size_t)node * 256 + lane * 4) = o;
  uint2 pk;
  pk.x = (unsigned)f2bf(o.x) | ((unsigned)f2bf(o.y) << 16);
  pk.y = (unsigned)f2bf(o.z) | ((unsigned)f2bf(o.w) << 16);
  *(uint2*)(outb + (size_t)node * 256 + lane * 4) = pk;
}

// ---------- LN2 ----------

__global__ __launch_bounds__(256) void ln2_kernel(
    const float* __restrict__ x1, const float* __restrict__ y,
    const float* __restrict__ g, const float* __restrict__ b,
    float* __restrict__ out) {
  __shared__ float red[4];
  const int row = blockIdx.x;
  const int t = threadIdx.x;
  float v = x1[(size_t)row * 256 + t] + y[(size_t)row * 256 + t];
  float s = v;
#pragma unroll
  for (int off = 32; off > 0; off >>= 1) s += __shfl_xor(s, off);
  if ((t & 63) == 0) red[t >> 6] = s;
  __syncthreads();
  float tot = red[0] + red[1] + red[2] + red[3];
  __syncthreads();
  const float mu = tot * (1.0f / 256.0f);
  const float d = v - mu;
  float vs = d * d;
#pragma unroll
  for (int off = 32; off > 0; off >>= 1) vs += __shfl_xor(vs, off);
  if ((t & 63) == 0) red[t >> 6] = vs;
  __syncthreads();
  float vtot = red[0] + red[1] + red[2] + red[3];
  const float r = rsqrtf(vtot * (1.0f / 256.0f) + 1e-5f);
  out[(size_t)row * 256 + t] = d * r * g[t] + b[t];
}

// ---------- launch ----------

extern "C" void kernel_launch(void* const* d_in, const int* in_sizes, int n_in,
                              void* d_out, int out_size, void* d_ws,
                              size_t ws_size, hipStream_t stream) {
  const float* x = (const float*)d_in[0];
  const int* ei = (const int*)d_in[1];
  const float* ew = (const float*)d_in[2];
  const float* wq = (const float*)d_in[3];
  const float* bq = (const float*)d_in[4];
  const float* wk = (const float*)d_in[5];
  const float* bk = (const float*)d_in[6];
  const float* wv = (const float*)d_in[7];
  const float* bv = (const float*)d_in[8];
  const float* wsm = (const float*)d_in[9];
  const float* bs = (const float*)d_in[10];
  const float* we = (const float*)d_in[11];
  const float* be = (const float*)d_in[12];
  const float* g1 = (const float*)d_in[13];
  const float* b1 = (const float*)d_in[14];
  const float* g2 = (const float*)d_in[15];
  const float* b2 = (const float*)d_in[16];
  const float* wff1 = (const float*)d_in[17];
  const float* bff1 = (const float*)d_in[18];
  const float* wff2 = (const float*)d_in[19];
  const float* bff2 = (const float*)d_in[20];
  float* out = (float*)d_out;

  unsigned short* qb = (unsigned short*)d_ws;        // 3 * N*256 bf16 (q,k,v)
  unsigned short* kbp = qb + 2560000;
  unsigned short* vbp = qb + 5120000;
  float* sbuf = (float*)(qb + 7680000);              // N*256 f32 (x + skip)
  uint2* es_csr = (uint2*)(sbuf + 2560000);          // N*BCAP x {src, eb}
  unsigned* cnt = (unsigned*)(es_csr + (size_t)N_NODES * BCAP);  // N
  float* x1 = (float*)(cnt + N_NODES);               // N*256
  float* y = x1 + 2560000;                           // N*256
  unsigned short* x1b = (unsigned short*)(y + 2560000);  // N*256 bf16
  unsigned short* h_b = x1b + 2560000;               // N*512 bf16
  unsigned short* xb = h_b;                          // alias (xb dead before h_b written)
  unsigned short* wt_qkvs = h_b + 5120000;           // 262144
  unsigned short* wt_ff1 = wt_qkvs + 262144;         // 131072
  unsigned short* wt_ff2 = wt_ff1 + 131072;          // 131072
  float* bias_qkvs = (float*)(wt_ff2 + 131072);      // 1024
  unsigned* pcnt = (unsigned*)(bias_qkvs + 1024);    // 256 (partition counters)
  uint2* pbuf = (uint2*)(pcnt + 256);                // P_PARTS*PCAP records (4MB)

  dim3 blk(256);
  const int mb = (N_NODES + 63) / 64;  // 157

  prep_all_kernel<<<(PREP_TOTAL + 255) / 256, blk, 0, stream>>>(
      wq, wk, wv, wsm, bq, bk, bv, bs, wff1, wff2, x,
      wt_qkvs, bias_qkvs, wt_ff1, wt_ff2, xb, pcnt);

  // edge partition sort pass 1 (157 blocks; EPT=4)
  scatter_p1<<<(N_EDGES + 512 * EPT - 1) / (512 * EPT), dim3(512), 0, stream>>>(
      ei, ew, we, be, pcnt, pbuf);

  // q,k,v (bf16) + sbuf = x + x@ws + bs (f32), WITH scatter pass-2 fused as
  // the first 250 blocks of the flattened grid (independent work, overlaps)
  mfma_gemm<0, 0, 0, 1><<<dim3(P_PARTS + 16 * mb), blk, 0, stream>>>(
      xb, 256, wt_qkvs, bias_qkvs, x, sbuf, 0, qb, 0, N_NODES, 256,
      pcnt, pbuf, cnt, es_csr);

  agg_fused_kernel<<<N_NODES, dim3(64), 0, stream>>>(
      cnt, es_csr, qb, kbp, vbp, sbuf, g1, b1, x1, x1b);

  // h = gelu(x1 @ wff1 + bff1) (bf16)  [64^2 tile, (8,157)]
  mfma_gemm<1, 0, 1, 0><<<dim3(8, mb), blk, 0, stream>>>(
      x1b, 256, wt_ff1, bff1, nullptr, (float*)nullptr, 0, h_b, 512, N_NODES, 256,
      nullptr, nullptr, nullptr, nullptr);

  // y = h @ wff2 + bff2 (f32)  [64^2 tile, (4,157)]
  mfma_gemm<0, 1, 0, 0><<<dim3(4, mb), blk, 0, stream>>>(
      h_b, 512, wt_ff2, bff2, nullptr, y, 256, (unsigned short*)nullptr, 0, N_NODES, 512,
      nullptr, nullptr, nullptr, nullptr);

  ln2_kernel<<<N_NODES, blk, 0, stream>>>(x1, y, g2, b2, out);
}